// Round 3
// baseline (624.662 us; speedup 1.0000x reference)
//
#include <hip/hip_runtime.h>

typedef __bf16 bf16x8 __attribute__((ext_vector_type(8)));
typedef float f32x4 __attribute__((ext_vector_type(4)));
typedef unsigned short u16;

#define HEADS 12
#define DK 64
#define DM 768
#define SEQL 4096
#define BSZ 2
#define MROWS (BSZ * SEQL) /* 8192 */

__device__ __forceinline__ float bf2f(u16 x) {
    unsigned int u = ((unsigned int)x) << 16;
    return __uint_as_float(u);
}
__device__ __forceinline__ u16 f2bf(float f) {
    unsigned int u = __float_as_uint(f);
    u += 0x7fff + ((u >> 16) & 1);   // round-to-nearest-even
    return (u16)(u >> 16);
}

// Detect whether the float tensors are really f32 (reference dtype) or bf16.
// bf16 N(0,1) data has no exp==0xFF patterns; f32 data read as u16 halves has
// ~1/256 rate in the low-mantissa halves. Writes 1 to *flag if f32.
__global__ void detect_dtype(const u16* __restrict__ q, int* __restrict__ flag) {
    __shared__ int cnt;
    if (threadIdx.x == 0) cnt = 0;
    __syncthreads();
    int c = 0;
    for (int i = threadIdx.x; i < 16384; i += 256) {
        u16 x = q[i];
        if (((x >> 7) & 0xFF) == 0xFF) c++;
    }
    if (c) atomicAdd(&cnt, c);
    __syncthreads();
    if (threadIdx.x == 0) *flag = (cnt > 0) ? 1 : 0;
}

// Stage 8 contiguous elements into LDS as bf16, from either dtype.
__device__ __forceinline__ void stage8_bf16(u16* dst, const u16* src) {
    *(uint4*)dst = *(const uint4*)src;
}
__device__ __forceinline__ void stage8_f32(u16* dst, const float* src) {
    float4 f0 = ((const float4*)src)[0];
    float4 f1 = ((const float4*)src)[1];
    ushort4 a = {f2bf(f0.x), f2bf(f0.y), f2bf(f0.z), f2bf(f0.w)};
    ushort4 b = {f2bf(f1.x), f2bf(f1.y), f2bf(f1.z), f2bf(f1.w)};
    *(ushort4*)dst = a;
    *(ushort4*)(dst + 4) = b;
}

// Y = X (8192x768) @ W^T (768x768) + b, fp32 accum.
// MODE 0: plain row-major Y[row*768+o] (dtype follows flag)
// MODE 1: head-split   Y[((b*12+h)<<18) + (s<<6) + d]  bf16 (for Q, K)
// MODE 2: head-split-T Y[((b*12+h)<<18) + (d<<12) + s] bf16 (for V)
// XFLAG: X dtype follows flag (raw input) vs always-bf16 (workspace ctx).
template <int MODE, bool XFLAG>
__global__ __launch_bounds__(256) void gemm_proj(const void* __restrict__ Xv,
                                                 const void* __restrict__ Wv,
                                                 const void* __restrict__ biasv,
                                                 void* __restrict__ Yv,
                                                 const int* __restrict__ flag) {
    __shared__ __align__(16) u16 As[64][40];  // 64 rows x BK=32 (+8 pad) bf16
    __shared__ __align__(16) u16 Bs[64][40];

    const int f32mode = *flag;
    const bool xf = XFLAG && f32mode;
    const bool wf = f32mode != 0;

    const int tid  = threadIdx.x;
    const int lane = tid & 63;
    const int wave = tid >> 6;
    const int wrow = (wave >> 1) * 32;
    const int wcol = (wave & 1) * 32;
    const int l15  = lane & 15;
    const int quad = lane >> 4;
    const int m0   = blockIdx.x * 64;
    const int n0   = blockIdx.y * 64;

    const int srow = tid >> 2;        // 0..63
    const int scol = (tid & 3) * 8;   // 0,8,16,24

    f32x4 acc[2][2] = {};
    const size_t xoff = (size_t)(m0 + srow) * DM + scol;
    const size_t woff = (size_t)(n0 + srow) * DM + scol;

    for (int kb = 0; kb < DM; kb += 32) {
        if (xf) stage8_f32(&As[srow][scol], (const float*)Xv + xoff + kb);
        else    stage8_bf16(&As[srow][scol], (const u16*)Xv + xoff + kb);
        if (wf) stage8_f32(&Bs[srow][scol], (const float*)Wv + woff + kb);
        else    stage8_bf16(&Bs[srow][scol], (const u16*)Wv + woff + kb);
        __syncthreads();
        bf16x8 a0 = *(const bf16x8*)&As[wrow + l15][quad * 8];
        bf16x8 a1 = *(const bf16x8*)&As[wrow + 16 + l15][quad * 8];
        bf16x8 b0 = *(const bf16x8*)&Bs[wcol + l15][quad * 8];
        bf16x8 b1 = *(const bf16x8*)&Bs[wcol + 16 + l15][quad * 8];
        acc[0][0] = __builtin_amdgcn_mfma_f32_16x16x32_bf16(a0, b0, acc[0][0], 0, 0, 0);
        acc[0][1] = __builtin_amdgcn_mfma_f32_16x16x32_bf16(a0, b1, acc[0][1], 0, 0, 0);
        acc[1][0] = __builtin_amdgcn_mfma_f32_16x16x32_bf16(a1, b0, acc[1][0], 0, 0, 0);
        acc[1][1] = __builtin_amdgcn_mfma_f32_16x16x32_bf16(a1, b1, acc[1][1], 0, 0, 0);
        __syncthreads();
    }

#pragma unroll
    for (int tm = 0; tm < 2; ++tm)
#pragma unroll
        for (int tn = 0; tn < 2; ++tn) {
            int o = n0 + wcol + tn * 16 + l15;
            float bv = wf ? ((const float*)biasv)[o] : bf2f(((const u16*)biasv)[o]);
#pragma unroll
            for (int r = 0; r < 4; ++r) {
                int row = m0 + wrow + tm * 16 + quad * 4 + r;
                float val = acc[tm][tn][r] + bv;
                if (MODE == 0) {
                    if (f32mode) ((float*)Yv)[(size_t)row * DM + o] = val;
                    else         ((u16*)Yv)[(size_t)row * DM + o] = f2bf(val);
                } else {
                    int b = row >> 12, s = row & (SEQL - 1);
                    int h = o >> 6, d = o & 63;
                    if (MODE == 1)
                        ((u16*)Yv)[((b * HEADS + h) << 18) + (s << 6) + d] = f2bf(val);
                    else
                        ((u16*)Yv)[((b * HEADS + h) << 18) + (d << 12) + s] = f2bf(val);
                }
            }
        }
}

// Flash attention. Q,K: [b][h][s][d]; Vt: [b][h][d][s]; ctx out: [b][s][h*64+d]
// All bf16 (workspace). Block: 256 thr = 4 waves, each wave owns 16 q-rows.
__global__ __launch_bounds__(256) void flash_attn(const u16* __restrict__ Q,
                                                  const u16* __restrict__ K,
                                                  const u16* __restrict__ Vt,
                                                  const int* __restrict__ mask,
                                                  u16* __restrict__ ctx) {
    __shared__ __align__(16) u16 Ks[64][72];      // [kpos][d]
    __shared__ __align__(16) u16 Vs[64][72];      // [d][kpos]
    __shared__ __align__(16) u16 Ps[4][16][72];   // per-wave P [q][kpos]

    const int tid  = threadIdx.x;
    const int lane = tid & 63;
    const int wave = tid >> 6;
    const int l15  = lane & 15;
    const int quad = lane >> 4;

    const int bh = blockIdx.y;
    const int b  = bh / HEADS;
    const int h  = bh - b * HEADS;
    const int q0 = blockIdx.x * 64 + wave * 16;

    const u16* Qh = Q + ((size_t)bh << 18);
    const u16* Kh = K + ((size_t)bh << 18);
    const u16* Vh = Vt + ((size_t)bh << 18);

    bf16x8 aq0 = *(const bf16x8*)&Qh[(q0 + l15) * DK + quad * 8];
    bf16x8 aq1 = *(const bf16x8*)&Qh[(q0 + l15) * DK + 32 + quad * 8];

    float m_r[4], l_r[4];
    f32x4 o_acc[4] = {};
#pragma unroll
    for (int r = 0; r < 4; ++r) { m_r[r] = -1e30f; l_r[r] = 0.f; }

    const int srow = tid >> 3;        // 0..31
    const int scol = (tid & 7) * 8;   // 0..56
    const int* maskb = mask + b * SEQL;

    for (int kt = 0; kt < SEQL; kt += 64) {
        *(uint4*)&Ks[srow][scol]      = *(const uint4*)&Kh[(kt + srow) * DK + scol];
        *(uint4*)&Ks[srow + 32][scol] = *(const uint4*)&Kh[(kt + srow + 32) * DK + scol];
        *(uint4*)&Vs[srow][scol]      = *(const uint4*)&Vh[srow * SEQL + kt + scol];
        *(uint4*)&Vs[srow + 32][scol] = *(const uint4*)&Vh[(srow + 32) * SEQL + kt + scol];
        __syncthreads();

        // S tile: 16 q-rows x 64 kpos
        f32x4 sv[4];
#pragma unroll
        for (int nt = 0; nt < 4; ++nt) {
            f32x4 z = {};
            bf16x8 bk0 = *(const bf16x8*)&Ks[nt * 16 + l15][quad * 8];
            bf16x8 bk1 = *(const bf16x8*)&Ks[nt * 16 + l15][32 + quad * 8];
            z = __builtin_amdgcn_mfma_f32_16x16x32_bf16(aq0, bk0, z, 0, 0, 0);
            z = __builtin_amdgcn_mfma_f32_16x16x32_bf16(aq1, bk1, z, 0, 0, 0);
            int mk = maskb[kt + nt * 16 + l15];
#pragma unroll
            for (int r = 0; r < 4; ++r) {
                float s = z[r] * 0.125f;
                if (mk == 0) s = -1e9f;
                z[r] = s;
            }
            sv[nt] = z;
        }

        // online softmax per row (row = quad*4+r; 16 cols live in lanes of the quad)
        float alpha[4];
#pragma unroll
        for (int r = 0; r < 4; ++r) {
            float mx = fmaxf(fmaxf(sv[0][r], sv[1][r]), fmaxf(sv[2][r], sv[3][r]));
#pragma unroll
            for (int off = 1; off < 16; off <<= 1) mx = fmaxf(mx, __shfl_xor(mx, off, 64));
            float newm = fmaxf(m_r[r], mx);
            alpha[r] = __expf(m_r[r] - newm);
            float rs = 0.f;
#pragma unroll
            for (int nt = 0; nt < 4; ++nt) {
                float p = __expf(sv[nt][r] - newm);
                sv[nt][r] = p;
                rs += p;
            }
#pragma unroll
            for (int off = 1; off < 16; off <<= 1) rs += __shfl_xor(rs, off, 64);
            l_r[r] = l_r[r] * alpha[r] + rs;
            m_r[r] = newm;
        }
#pragma unroll
        for (int dv = 0; dv < 4; ++dv)
#pragma unroll
            for (int r = 0; r < 4; ++r) o_acc[dv][r] *= alpha[r];

        // P: C/D layout -> A layout via LDS round-trip (barrier-ordered)
#pragma unroll
        for (int nt = 0; nt < 4; ++nt)
#pragma unroll
            for (int r = 0; r < 4; ++r)
                Ps[wave][quad * 4 + r][nt * 16 + l15] = f2bf(sv[nt][r]);
        __syncthreads();

        bf16x8 ap0 = *(const bf16x8*)&Ps[wave][l15][quad * 8];
        bf16x8 ap1 = *(const bf16x8*)&Ps[wave][l15][32 + quad * 8];
#pragma unroll
        for (int dv = 0; dv < 4; ++dv) {
            bf16x8 bv0 = *(const bf16x8*)&Vs[dv * 16 + l15][quad * 8];
            bf16x8 bv1 = *(const bf16x8*)&Vs[dv * 16 + l15][32 + quad * 8];
            o_acc[dv] = __builtin_amdgcn_mfma_f32_16x16x32_bf16(ap0, bv0, o_acc[dv], 0, 0, 0);
            o_acc[dv] = __builtin_amdgcn_mfma_f32_16x16x32_bf16(ap1, bv1, o_acc[dv], 0, 0, 0);
        }
        __syncthreads();
    }

    float inv_l[4];
#pragma unroll
    for (int r = 0; r < 4; ++r) inv_l[r] = 1.f / l_r[r];
#pragma unroll
    for (int dv = 0; dv < 4; ++dv)
#pragma unroll
        for (int r = 0; r < 4; ++r) {
            int s = q0 + quad * 4 + r;
            int col = h * DK + dv * 16 + l15;
            ctx[(size_t)(b * SEQL + s) * DM + col] = f2bf(o_acc[dv][r] * inv_l[r]);
        }
}

extern "C" void kernel_launch(void* const* d_in, const int* in_sizes, int n_in,
                              void* d_out, int out_size, void* d_ws, size_t ws_size,
                              hipStream_t stream) {
    const void* q   = d_in[0];
    const void* k   = d_in[1];
    const void* v   = d_in[2];
    const void* Wq  = d_in[3];
    const void* bq  = d_in[4];
    const void* Wk  = d_in[5];
    const void* bk  = d_in[6];
    const void* Wv  = d_in[7];
    const void* bv  = d_in[8];
    const void* Wo  = d_in[9];
    const void* bo  = d_in[10];
    const int* mask = (const int*)d_in[11];

    const size_t NSH = (size_t)BSZ * HEADS * SEQL * DK;  // 6291456 elems
    const size_t need = 4 * NSH * sizeof(u16) + 256;
    if (ws_size < need) return;  // diagnostic: too-small ws -> absmax == max|ref|

    u16* ws  = (u16*)d_ws;
    u16* Qh  = ws;
    u16* Kh  = ws + NSH;
    u16* Vth = ws + 2 * NSH;
    u16* ctx = ws + 3 * NSH;
    int* dflag = (int*)((char*)d_ws + 4 * NSH * sizeof(u16));

    detect_dtype<<<1, 256, 0, stream>>>((const u16*)q, dflag);

    dim3 gg(MROWS / 64, DM / 64);
    gemm_proj<1, true><<<gg, 256, 0, stream>>>(q, Wq, bq, Qh, dflag);
    gemm_proj<1, true><<<gg, 256, 0, stream>>>(k, Wk, bk, Kh, dflag);
    gemm_proj<2, true><<<gg, 256, 0, stream>>>(v, Wv, bv, Vth, dflag);
    flash_attn<<<dim3(SEQL / 64, BSZ * HEADS), 256, 0, stream>>>(Qh, Kh, Vth, mask, ctx);
    gemm_proj<0, false><<<gg, 256, 0, stream>>>(ctx, Wo, bo, d_out, dflag);
}

// Round 4
// 501.309 us; speedup vs baseline: 1.2461x; 1.2461x over previous
//
#include <hip/hip_runtime.h>
#include <hip/hip_bf16.h>

typedef __bf16 bf16x8 __attribute__((ext_vector_type(8)));
typedef float f32x4 __attribute__((ext_vector_type(4)));
typedef unsigned short u16;

#define HEADS 12
#define DK 64
#define DM 768
#define SEQL 4096
#define BSZ 2
#define MROWS (BSZ * SEQL) /* 8192 */

__device__ __forceinline__ float bf2f(u16 x) {
    unsigned int u = ((unsigned int)x) << 16;
    return __uint_as_float(u);
}
__device__ __forceinline__ u16 f2bf(float f) {
    unsigned int u = __float_as_uint(f);
    u += 0x7fff + ((u >> 16) & 1);   // round-to-nearest-even
    return (u16)(u >> 16);
}

// Detect whether the float tensors are really f32 (reference dtype) or bf16.
__global__ void detect_dtype(const u16* __restrict__ q, int* __restrict__ flag) {
    __shared__ int cnt;
    if (threadIdx.x == 0) cnt = 0;
    __syncthreads();
    int c = 0;
    for (int i = threadIdx.x; i < 16384; i += 256) {
        u16 x = q[i];
        if (((x >> 7) & 0xFF) == 0xFF) c++;
    }
    if (c) atomicAdd(&cnt, c);
    __syncthreads();
    if (threadIdx.x == 0) *flag = (cnt > 0) ? 1 : 0;
}

__device__ __forceinline__ void stage8_bf16(u16* dst, const u16* src) {
    *(uint4*)dst = *(const uint4*)src;
}
__device__ __forceinline__ void stage8_f32(u16* dst, const float* src) {
    float4 f0 = ((const float4*)src)[0];
    float4 f1 = ((const float4*)src)[1];
    ushort4 a = {f2bf(f0.x), f2bf(f0.y), f2bf(f0.z), f2bf(f0.w)};
    ushort4 b = {f2bf(f1.x), f2bf(f1.y), f2bf(f1.z), f2bf(f1.w)};
    *(ushort4*)dst = a;
    *(ushort4*)(dst + 4) = b;
}

// Y = X (8192x768) @ W^T (768x768) + b, fp32 accum. (unchanged from R3 — proven)
template <int MODE, bool XFLAG>
__global__ __launch_bounds__(256) void gemm_proj(const void* __restrict__ Xv,
                                                 const void* __restrict__ Wv,
                                                 const void* __restrict__ biasv,
                                                 void* __restrict__ Yv,
                                                 const int* __restrict__ flag) {
    __shared__ __align__(16) u16 As[64][40];
    __shared__ __align__(16) u16 Bs[64][40];

    const int f32mode = *flag;
    const bool xf = XFLAG && f32mode;
    const bool wf = f32mode != 0;

    const int tid  = threadIdx.x;
    const int lane = tid & 63;
    const int wave = tid >> 6;
    const int wrow = (wave >> 1) * 32;
    const int wcol = (wave & 1) * 32;
    const int l15  = lane & 15;
    const int quad = lane >> 4;
    const int m0   = blockIdx.x * 64;
    const int n0   = blockIdx.y * 64;

    const int srow = tid >> 2;
    const int scol = (tid & 3) * 8;

    f32x4 acc[2][2] = {};
    const size_t xoff = (size_t)(m0 + srow) * DM + scol;
    const size_t woff = (size_t)(n0 + srow) * DM + scol;

    for (int kb = 0; kb < DM; kb += 32) {
        if (xf) stage8_f32(&As[srow][scol], (const float*)Xv + xoff + kb);
        else    stage8_bf16(&As[srow][scol], (const u16*)Xv + xoff + kb);
        if (wf) stage8_f32(&Bs[srow][scol], (const float*)Wv + woff + kb);
        else    stage8_bf16(&Bs[srow][scol], (const u16*)Wv + woff + kb);
        __syncthreads();
        bf16x8 a0 = *(const bf16x8*)&As[wrow + l15][quad * 8];
        bf16x8 a1 = *(const bf16x8*)&As[wrow + 16 + l15][quad * 8];
        bf16x8 b0 = *(const bf16x8*)&Bs[wcol + l15][quad * 8];
        bf16x8 b1 = *(const bf16x8*)&Bs[wcol + 16 + l15][quad * 8];
        acc[0][0] = __builtin_amdgcn_mfma_f32_16x16x32_bf16(a0, b0, acc[0][0], 0, 0, 0);
        acc[0][1] = __builtin_amdgcn_mfma_f32_16x16x32_bf16(a0, b1, acc[0][1], 0, 0, 0);
        acc[1][0] = __builtin_amdgcn_mfma_f32_16x16x32_bf16(a1, b0, acc[1][0], 0, 0, 0);
        acc[1][1] = __builtin_amdgcn_mfma_f32_16x16x32_bf16(a1, b1, acc[1][1], 0, 0, 0);
        __syncthreads();
    }

#pragma unroll
    for (int tm = 0; tm < 2; ++tm)
#pragma unroll
        for (int tn = 0; tn < 2; ++tn) {
            int o = n0 + wcol + tn * 16 + l15;
            float bv = wf ? ((const float*)biasv)[o] : bf2f(((const u16*)biasv)[o]);
#pragma unroll
            for (int r = 0; r < 4; ++r) {
                int row = m0 + wrow + tm * 16 + quad * 4 + r;
                float val = acc[tm][tn][r] + bv;
                if (MODE == 0) {
                    if (f32mode) ((float*)Yv)[(size_t)row * DM + o] = val;
                    else         ((u16*)Yv)[(size_t)row * DM + o] = f2bf(val);
                } else {
                    int b = row >> 12, s = row & (SEQL - 1);
                    int h = o >> 6, d = o & 63;
                    if (MODE == 1)
                        ((u16*)Yv)[((b * HEADS + h) << 18) + (s << 6) + d] = f2bf(val);
                    else
                        ((u16*)Yv)[((b * HEADS + h) << 18) + (d << 12) + s] = f2bf(val);
                }
            }
        }
}

// ---- flash v2 ----
typedef __attribute__((address_space(1))) unsigned int glb_u32;
typedef __attribute__((address_space(3))) unsigned int lds_u32;

__device__ __forceinline__ void gld16(const u16* g, u16* l) {
    __builtin_amdgcn_global_load_lds((glb_u32*)g, (lds_u32*)l, 16, 0, 0);
}

// Stage a 64-row x 64-col bf16 tile (rows strided by rstride elems in global)
// into 8KB of LDS via global_load_lds, XOR-swizzling 16B chunks: LDS slot
// (row, p) holds global chunk (row, p ^ (row&7)).
__device__ __forceinline__ void stage_tile(const u16* gbase, int rstride,
                                           u16* lbase, int tid) {
#pragma unroll
    for (int it = 0; it < 2; ++it) {
        int c = it * 256 + tid;      // 0..511 chunk id
        int row = c >> 3, p = c & 7;
        int gc = p ^ (row & 7);
        gld16(gbase + (size_t)row * rstride + gc * 8, lbase + c * 8);
    }
}

// Q,K: [b][h][s][d]; Vt: [b][h][d][s]; ctx out: [b][s][h*64+d]
// 256 thr = 4 waves, each wave owns 16 q-rows. S^T layout: each lane owns ONE
// q-row (q = lane&15); softmax needs only 2 cross-quad shuffles.
__global__ __launch_bounds__(256) void flash_attn(const u16* __restrict__ Q,
                                                  const u16* __restrict__ K,
                                                  const u16* __restrict__ Vt,
                                                  const int* __restrict__ mask,
                                                  u16* __restrict__ ctx) {
    __shared__ __align__(16) u16 Ks[2][64 * 64];
    __shared__ __align__(16) u16 Vs[2][64 * 64];
    __shared__ __align__(16) float Ms[2][64];
    __shared__ __align__(16) u16 Ps[4][16 * 72];   // per-wave [q][kpos] (pad 72)

    const int tid  = threadIdx.x;
    const int lane = tid & 63;
    const int wave = tid >> 6;
    const int l15  = lane & 15;
    const int quad = lane >> 4;

    const int bh = blockIdx.y;
    const int b  = bh / HEADS;
    const int h  = bh - b * HEADS;
    const int qb = blockIdx.x * 64 + wave * 16;

    const u16* Qh = Q  + ((size_t)bh << 18);
    const u16* Kh = K  + ((size_t)bh << 18);
    const u16* Vh = Vt + ((size_t)bh << 18);
    const int* maskb = mask + b * SEQL;

    // Q fragment = B-operand of S^T = K·Q^T:  B[k=dk][n=q], n=l15 -> q
    bf16x8 aq0 = *(const bf16x8*)&Qh[(size_t)(qb + l15) * DK + quad * 8];
    bf16x8 aq1 = *(const bf16x8*)&Qh[(size_t)(qb + l15) * DK + 32 + quad * 8];

    // swizzled chunk byte-groups for Ks/Vs fragment reads
    const int r7   = l15 & 7;
    const int ck0  = (quad ^ r7) * 8;          // k/kpos 0..31  (chunk = quad)
    const int ck1  = ((quad + 4) ^ r7) * 8;    // k/kpos 32..63 (chunk = 4+quad)
    const int lrow = l15 * 64;

    float m_s = -3.0e38f, l_s = 0.f;
    f32x4 o_acc[4] = {};

    int mreg = 0;
    if (tid < 64) mreg = maskb[tid];
    stage_tile(Kh, DK, &Ks[0][0], tid);
    stage_tile(Vh, SEQL, &Vs[0][0], tid);
    if (tid < 64) {
        Ms[0][tid] = (mreg == 0) ? -1.0e9f : 0.0f;
        mreg = maskb[64 + tid];
    }
    __syncthreads();   // drains global_load_lds (vmcnt) + orders Ms

    for (int t = 0; t < 64; ++t) {
        const int cur = t & 1, nxt = cur ^ 1;
        if (t < 63) {   // prefetch next tile; drained by this iter's end barrier
            const int kt = (t + 1) * 64;
            stage_tile(Kh + (size_t)kt * DK, DK, &Ks[nxt][0], tid);
            stage_tile(Vh + kt, SEQL, &Vs[nxt][0], tid);
            if (tid < 64) {
                Ms[nxt][tid] = (mreg == 0) ? -1.0e9f : 0.0f;
                if (t < 62) mreg = maskb[(t + 2) * 64 + tid];
            }
        }

        const u16* kb = &Ks[cur][0];
        const u16* vb = &Vs[cur][0];

        // S^T tile: lane holds q=l15, kpos = nt*16 + quad*4 + r
        f32x4 s4[4];
#pragma unroll
        for (int nt = 0; nt < 4; ++nt) {
            bf16x8 ak0 = *(const bf16x8*)&kb[lrow + nt * 1024 + ck0];
            bf16x8 ak1 = *(const bf16x8*)&kb[lrow + nt * 1024 + ck1];
            f32x4 z = {};
            z = __builtin_amdgcn_mfma_f32_16x16x32_bf16(ak0, aq0, z, 0, 0, 0);
            z = __builtin_amdgcn_mfma_f32_16x16x32_bf16(ak1, aq1, z, 0, 0, 0);
            f32x4 bias = *(const f32x4*)&Ms[cur][nt * 16 + quad * 4];
#pragma unroll
            for (int r = 0; r < 4; ++r) s4[nt][r] = z[r] * 0.125f + bias[r];
        }

        // online softmax, one q-row per lane
        float mx = -3.0e38f;
#pragma unroll
        for (int nt = 0; nt < 4; ++nt)
#pragma unroll
            for (int r = 0; r < 4; ++r) mx = fmaxf(mx, s4[nt][r]);
        mx = fmaxf(mx, __shfl_xor(mx, 16, 64));
        mx = fmaxf(mx, __shfl_xor(mx, 32, 64));
        float newm = fmaxf(m_s, mx);
        float alpha = __expf(m_s - newm);
        float rs = 0.f;
#pragma unroll
        for (int nt = 0; nt < 4; ++nt)
#pragma unroll
            for (int r = 0; r < 4; ++r) {
                float p = __expf(s4[nt][r] - newm);
                s4[nt][r] = p;
                rs += p;
            }
        rs += __shfl_xor(rs, 16, 64);
        rs += __shfl_xor(rs, 32, 64);
        l_s = l_s * alpha + rs;
        m_s = newm;
#pragma unroll
        for (int dv = 0; dv < 4; ++dv)
#pragma unroll
            for (int r = 0; r < 4; ++r) o_acc[dv][r] *= alpha;

        // P^T into per-wave LDS slice: Ps[q=l15][kpos] (wave-private, no barrier)
#pragma unroll
        for (int nt = 0; nt < 4; ++nt) {
            union { __hip_bfloat162 h2[2]; uint2 u; } cv;
            cv.h2[0] = __float22bfloat162_rn(make_float2(s4[nt][0], s4[nt][1]));
            cv.h2[1] = __float22bfloat162_rn(make_float2(s4[nt][2], s4[nt][3]));
            *(uint2*)&Ps[wave][l15 * 72 + nt * 16 + quad * 4] = cv.u;
        }
        asm volatile("" ::: "memory");  // order same-wave LDS write -> read

        // PV: ctx^T = V^T · P^T
        bf16x8 bp0 = *(const bf16x8*)&Ps[wave][l15 * 72 + quad * 8];
        bf16x8 bp1 = *(const bf16x8*)&Ps[wave][l15 * 72 + 32 + quad * 8];
#pragma unroll
        for (int dv = 0; dv < 4; ++dv) {
            bf16x8 av0 = *(const bf16x8*)&vb[lrow + dv * 1024 + ck0];
            bf16x8 av1 = *(const bf16x8*)&vb[lrow + dv * 1024 + ck1];
            o_acc[dv] = __builtin_amdgcn_mfma_f32_16x16x32_bf16(av0, bp0, o_acc[dv], 0, 0, 0);
            o_acc[dv] = __builtin_amdgcn_mfma_f32_16x16x32_bf16(av1, bp1, o_acc[dv], 0, 0, 0);
        }
        __syncthreads();   // single barrier: frees cur, drains nxt prefetch
    }

    // epilogue: normalize, transpose through per-wave Ps, coalesced store
    float inv = 1.0f / l_s;   // lane's q = l15 matches o_acc columns
#pragma unroll
    for (int dv = 0; dv < 4; ++dv) {
        union { __hip_bfloat162 h2[2]; uint2 u; } cv;
        cv.h2[0] = __float22bfloat162_rn(make_float2(o_acc[dv][0] * inv, o_acc[dv][1] * inv));
        cv.h2[1] = __float22bfloat162_rn(make_float2(o_acc[dv][2] * inv, o_acc[dv][3] * inv));
        *(uint2*)&Ps[wave][l15 * 72 + dv * 16 + quad * 4] = cv.u;   // Ps[q][d]
    }
    asm volatile("" ::: "memory");
    {
        int rowq = lane >> 2, dchunk = lane & 3;
        uint4 w0 = *(const uint4*)&Ps[wave][rowq * 72 + dchunk * 16];
        uint4 w1 = *(const uint4*)&Ps[wave][rowq * 72 + dchunk * 16 + 8];
        size_t orow = (size_t)(b * SEQL + qb + rowq) * DM + h * DK + dchunk * 16;
        *(uint4*)&ctx[orow] = w0;
        *(uint4*)&ctx[orow + 8] = w1;
    }
}

extern "C" void kernel_launch(void* const* d_in, const int* in_sizes, int n_in,
                              void* d_out, int out_size, void* d_ws, size_t ws_size,
                              hipStream_t stream) {
    const void* q   = d_in[0];
    const void* k   = d_in[1];
    const void* v   = d_in[2];
    const void* Wq  = d_in[3];
    const void* bq  = d_in[4];
    const void* Wk  = d_in[5];
    const void* bk  = d_in[6];
    const void* Wv  = d_in[7];
    const void* bv  = d_in[8];
    const void* Wo  = d_in[9];
    const void* bo  = d_in[10];
    const int* mask = (const int*)d_in[11];

    const size_t NSH = (size_t)BSZ * HEADS * SEQL * DK;  // 6291456 elems
    const size_t need = 4 * NSH * sizeof(u16) + 256;
    if (ws_size < need) return;

    u16* ws  = (u16*)d_ws;
    u16* Qh  = ws;
    u16* Kh  = ws + NSH;
    u16* Vth = ws + 2 * NSH;
    u16* ctx = ws + 3 * NSH;
    int* dflag = (int*)((char*)d_ws + 4 * NSH * sizeof(u16));

    detect_dtype<<<1, 256, 0, stream>>>((const u16*)q, dflag);

    dim3 gg(MROWS / 64, DM / 64);
    gemm_proj<1, true><<<gg, 256, 0, stream>>>(q, Wq, bq, Qh, dflag);
    gemm_proj<1, true><<<gg, 256, 0, stream>>>(k, Wk, bk, Kh, dflag);
    gemm_proj<2, true><<<gg, 256, 0, stream>>>(v, Wv, bv, Vth, dflag);
    flash_attn<<<dim3(SEQL / 64, BSZ * HEADS), 256, 0, stream>>>(Qh, Kh, Vth, mask, ctx);
    gemm_proj<0, false><<<gg, 256, 0, stream>>>(ctx, Wo, bo, d_out, dflag);
}